// Round 4
// baseline (1863.907 us; speedup 1.0000x reference)
//
#include <hip/hip_runtime.h>
#include <hip/hip_fp16.h>

// ---------------------------------------------------------------------------
// 4-layer GRU stack (Keras reset_after), B=128, T=384, U=D=256.
//
// R4: 64 persistent blocks = 4 layers x 8 chunks(16 rows) x 2 HALVES(128 u).
// Each block: 512 thr = 8 waves; wave w owns units 128e+16w..+15 -> holds the
// z,r,h B-tiles for those units in VGPRs (48 frags = 192 VGPR) and computes
// gates fully in-wave from its own MFMA accumulators (no LDS scatter).
// Per step per block: M=16, N=384, K=512 (input+recurrent unified), 48
// MFMA/wave. Own-half h(t) is written directly into the LDS A-fragment
// buffer (never leaves the CU). Only the partner half (128 units) crosses
// blocks, via R0's PROVEN epoch-tagged 8-byte-word MALL ring (prefetch at
// step t, validate at t+1). Inter-layer input staging = R0's stage_x
// verbatim. Ring backpressure = R0's flag scheme (2 flags per group).
// vs R0: 2-way coupling instead of 8-way, and the own-h global round trip
// is eliminated entirely.
// ---------------------------------------------------------------------------

#define LAYERS 4
#define TSTEPS 384
#define NCH    8
#define WPL    (48 * 16 * 64 * 8)  // repacked weight elems per layer
#define TILE_STRIDE (16 * 64 * 8)  // 8192 elems per 16-col tile
#define RING   16
#define SLOT_ULL (16 * 128)        // 16 rows x 128 tagged ulls per slot
#define GRP_ULL  (RING * SLOT_ULL)

typedef _Float16 half8 __attribute__((ext_vector_type(8)));
typedef float    f32x4 __attribute__((ext_vector_type(4)));
typedef unsigned uint4v __attribute__((ext_vector_type(4)));
typedef unsigned long long ull;

// ws layout (bytes)
#define WP_OFF   0
#define BP_OFF   (LAYERS * WPL * 2)                 // 3,145,728
#define FLAG_OFF (BP_OFF + LAYERS * 1024 * 4)       // +16 KB
#define FLAG_BYTES 4096
#define HBUF_OFF (4 * 1024 * 1024)                  // 4MB..12MB: h rings

#define SCOPE __HIP_MEMORY_SCOPE_AGENT
#define MFMA __builtin_amdgcn_mfma_f32_16x16x32_f16

// ---------------------------------------------------------------------------
// Repack: W[l] -> [tile=48][kt=16][lane=64][8] fp16 B-fragments.
// n = tile*16 + (lane&15), k = kt*32 + (lane>>4)*8 + j.
// Bias: [0:512]=b_in+b_rec (z,r), [512:768]=b_in_h, [768:1024]=b_rec_h.
// ---------------------------------------------------------------------------
__global__ void repack_kernel(const float* __restrict__ k0, const float* __restrict__ rk0,
                              const float* __restrict__ b0, const float* __restrict__ kern,
                              const float* __restrict__ rkern, const float* __restrict__ bias,
                              _Float16* __restrict__ Wp, float* __restrict__ Bp)
{
    int idx = blockIdx.x * 256 + threadIdx.x;
    const int total_w = LAYERS * WPL;
    if (idx < total_w) {
        int l = idx / WPL;
        int r = idx - l * WPL;
        int j    = r & 7;
        int lane = (r >> 3) & 63;
        int kt   = (r >> 9) & 15;
        int tile = r >> 13;
        int n = tile * 16 + (lane & 15);
        int k = kt * 32 + (lane >> 4) * 8 + j;
        float v;
        if (l == 0) {
            v = (k < 256) ? k0[(size_t)k * 768 + n] : rk0[(size_t)(k - 256) * 768 + n];
        } else {
            const float* kk = kern  + (size_t)(l - 1) * 256 * 768;
            const float* rk = rkern + (size_t)(l - 1) * 256 * 768;
            v = (k < 256) ? kk[(size_t)k * 768 + n] : rk[(size_t)(k - 256) * 768 + n];
        }
        Wp[idx] = (_Float16)v;
    } else {
        int ib = idx - total_w;
        if (ib < LAYERS * 1024) {
            int l = ib >> 10;
            int i = ib & 1023;
            const float* bs = (l == 0) ? b0 : (bias + (size_t)(l - 1) * 2 * 768);
            float v;
            if (i < 512)      v = bs[i] + bs[768 + i];
            else if (i < 768) v = bs[512 + (i - 512)];
            else              v = bs[768 + 512 + (i - 768)];
            Bp[l * 1024 + i] = v;
        }
    }
}

// ---------------------------------------------------------------------------
// Persistent GRU kernel.
// ---------------------------------------------------------------------------
__launch_bounds__(512, 2)
__global__ void gru_kernel(const float* __restrict__ x,
                           const _Float16* __restrict__ Wp,
                           const float* __restrict__ Bp,
                           ull* __restrict__ hbuf,
                           unsigned int* __restrict__ flags,
                           float* __restrict__ out)
{
    // A in MFMA fragment order: flat half index = (kt*64 + lane)*8 + j,
    // where A[row = lane&15][k = kt*32 + (lane>>4)*8 + j]. 2 buffers x 16 KB.
    __shared__ _Float16 Af[2][16 * 512];

    const int tid  = threadIdx.x;
    const int lane = tid & 63;
    const int w    = tid >> 6;
    const int lo16 = lane & 15;
    const int q    = lane >> 4;

    const int e = blockIdx.x & 1;          // half (units 128e..128e+127)
    const int c = (blockIdx.x >> 1) & 7;   // batch chunk
    const int l = blockIdx.x >> 4;         // layer
    const int g = l * NCH + c;
    const int b0row = c * 16;

    // ---- this wave's 3 weight tiles (z, r, h) -> 192 VGPRs ----
    half8 bzf[16], brf[16], bhf[16];
    {
        const _Float16* wb = Wp + (size_t)l * WPL;
        const int zt = 8 * e + w, rt = 16 + 8 * e + w, ht = 32 + 8 * e + w;
#pragma unroll
        for (int kt = 0; kt < 16; ++kt) {
            const size_t o = ((size_t)kt * 64 + lane) * 8;
            bzf[kt] = *(const half8*)(wb + (size_t)zt * TILE_STRIDE + o);
            brf[kt] = *(const half8*)(wb + (size_t)rt * TILE_STRIDE + o);
            bhf[kt] = *(const half8*)(wb + (size_t)ht * TILE_STRIDE + o);
        }
    }

    // ---- gate constants: this lane's unit ----
    const int u0 = 128 * e + 16 * w + lo16;
    float Bz, Br, Bi, Bh;
    {
        const float* bp = Bp + l * 1024;
        Bz = bp[u0]; Br = bp[256 + u0]; Bi = bp[512 + u0]; Bh = bp[768 + u0];
    }

    // ---- stage_x mapping (tid<256; R0 verbatim) ----
    const int grow = tid >> 4;
    const int g16  = tid & 15;
    const int gup  = g16 * 2;
    const int ktx  = g16 >> 1;
    const int qq   = (g16 & 1) * 2;
    const int xoff0 = ((ktx * 64) + qq * 16 + grow) * 8;
    const int xoff1 = ((ktx * 64) + (qq + 1) * 16 + grow) * 8;

    // ---- publish / partner-exchange mapping (512 threads) ----
    const int rr = tid >> 5;               // row 0..15
    const int k5 = tid & 31;
    const int uown = 128 * e + 4 * k5;     // 4 own units read for publish
    const int wown = 64 * e + 2 * k5;      // own ring word idx (2 words)
    const int upar = 128 * (1 - e) + 4 * k5;
    const int wpar = 64 * (1 - e) + 2 * k5;
    // half-elem offset of unit u, row r in Af (recurrent region kt 8..15)
    auto hoff = [](int u, int r) {
        return ((8 + (u >> 5)) * 64 + ((u & 31) >> 3) * 16 + r) * 8 + (u & 7);
    };
    const int po = hoff(uown, rr);         // publish read (8B aligned: uown%4==0)
    const int so = hoff(upar, rr);         // partner stage write (8B aligned)

    unsigned int* my_flag = flags + g * 2 + e;
    unsigned int* fl_dn   = flags + (g + NCH) * 2;       // valid only l<3

    ull*       hb_own = hbuf + (size_t)g * GRP_ULL;
    const ull* hb_up  = hbuf + (size_t)(l > 0 ? g - NCH : g) * GRP_ULL;

    auto wait_dn = [&](unsigned need) {
        for (;;) {
            unsigned v = 0xFFFFFFFFu;
            if (lane < 2)
                v = __hip_atomic_load(fl_dn + lane, __ATOMIC_RELAXED, SCOPE);
            if (__all((int)(v >= need))) return;
            __builtin_amdgcn_s_sleep(1);
        }
    };

    auto stage_x = [&](int t, _Float16* An) {   // R0 verbatim (tid<256)
        if (l == 0) {
            const float* sp = x + ((size_t)(b0row + grow) * TSTEPS + t) * 256 + gup * 8;
            f32x4 a0 = *(const f32x4*)sp,       a1 = *(const f32x4*)(sp + 4);
            f32x4 a2 = *(const f32x4*)(sp + 8), a3 = *(const f32x4*)(sp + 12);
            half8 h0, h1;
            h0[0]=(_Float16)a0[0]; h0[1]=(_Float16)a0[1]; h0[2]=(_Float16)a0[2]; h0[3]=(_Float16)a0[3];
            h0[4]=(_Float16)a1[0]; h0[5]=(_Float16)a1[1]; h0[6]=(_Float16)a1[2]; h0[7]=(_Float16)a1[3];
            h1[0]=(_Float16)a2[0]; h1[1]=(_Float16)a2[1]; h1[2]=(_Float16)a2[2]; h1[3]=(_Float16)a2[3];
            h1[4]=(_Float16)a3[0]; h1[5]=(_Float16)a3[1]; h1[6]=(_Float16)a3[2]; h1[7]=(_Float16)a3[3];
            *(half8*)(An + xoff0) = h0;
            *(half8*)(An + xoff1) = h1;
        } else {
            const ull* spx = hb_up + (size_t)(t & (RING - 1)) * SLOT_ULL + grow * 128 + g16 * 8;
            const unsigned tg = (unsigned)(t + 1);
            ull vx[8];
#pragma unroll
            for (int j = 0; j < 8; ++j)
                vx[j] = __hip_atomic_load(spx + j, __ATOMIC_RELAXED, SCOPE);
            for (;;) {
                bool ok = true;
#pragma unroll
                for (int j = 0; j < 8; ++j)
                    if ((unsigned)(vx[j] >> 32) != tg) {
                        vx[j] = __hip_atomic_load(spx + j, __ATOMIC_RELAXED, SCOPE);
                        ok = false;
                    }
                if (ok) break;
                __builtin_amdgcn_s_sleep(1);
            }
            uint4v w0, w1;
            w0[0]=(unsigned)vx[0]; w0[1]=(unsigned)vx[1]; w0[2]=(unsigned)vx[2]; w0[3]=(unsigned)vx[3];
            w1[0]=(unsigned)vx[4]; w1[1]=(unsigned)vx[5]; w1[2]=(unsigned)vx[6]; w1[3]=(unsigned)vx[7];
            *(uint4v*)(An + xoff0) = w0;
            *(uint4v*)(An + xoff1) = w1;
        }
    };

    // ---- prologue: x(0) into input half; zero recurrent half (kt 8..15) ----
    if (tid < 256) stage_x(0, Af[0]);
    {
        uint4v z = {0u, 0u, 0u, 0u};
        *(uint4v*)(Af[0] + ((8 + (tid >> 6)) * 64 + (tid & 63)) * 8) = z;
    }

    ull vh0, vh1;                          // prefetched partner tagged words
    float hpv[4] = {0.f, 0.f, 0.f, 0.f};

    for (int t = 0; t < TSTEPS; ++t) {
        _Float16* A  = Af[t & 1];
        _Float16* An = Af[(t + 1) & 1];

        // ---- stage 1: validate prefetched partner h(t-1), stage into A ----
        if (t > 0) {
            const ull* sp = hb_own + (size_t)((t - 1) & (RING - 1)) * SLOT_ULL + rr * 128 + wpar;
            const unsigned tg = (unsigned)t;
            for (;;) {
                bool ok = true;
                if ((unsigned)(vh0 >> 32) != tg) {
                    vh0 = __hip_atomic_load(sp + 0, __ATOMIC_RELAXED, SCOPE); ok = false;
                }
                if ((unsigned)(vh1 >> 32) != tg) {
                    vh1 = __hip_atomic_load(sp + 1, __ATOMIC_RELAXED, SCOPE); ok = false;
                }
                if (ok) break;
            }
            ull hv = ((ull)(unsigned)vh1 << 32) | (ull)(unsigned)vh0;
            *(ull*)(A + so) = hv;
        }
        __syncthreads();   // B1: A complete (input + own-h + partner-h)

        // ---- stage 2: MFMA — 48 per wave, wave-local gate columns ----
        f32x4 az = {0,0,0,0}, ar = {0,0,0,0}, ai = {0,0,0,0}, ah = {0,0,0,0};
#pragma unroll
        for (int kt = 0; kt < 16; ++kt) {
            half8 a = *(const half8*)(A + ((kt * 64) + lane) * 8);
            az = MFMA(a, bzf[kt], az, 0, 0, 0);
            ar = MFMA(a, brf[kt], ar, 0, 0, 0);
            if (kt < 8) ai = MFMA(a, bhf[kt], ai, 0, 0, 0);
            else        ah = MFMA(a, bhf[kt], ah, 0, 0, 0);
        }

        // ---- gates in-register; h(t) -> An recurrent region ----
        float hn[4];
#pragma unroll
        for (int j = 0; j < 4; ++j) {
            float zp = az[j] + Bz;
            float rp = ar[j] + Br;
            float ip = ai[j] + Bi;
            float hp = ah[j] + Bh;
            float z  = 1.f / (1.f + __expf(-zp));
            float r  = 1.f / (1.f + __expf(-rp));
            float pre = ip + r * hp;
            float ex  = __expf(2.f * pre);
            float th  = 1.f - 2.f / (ex + 1.f);
            hn[j] = z * hpv[j] + (1.f - z) * th;
            hpv[j] = hn[j];
        }
#pragma unroll
        for (int j = 0; j < 4; ++j)
            An[hoff(u0, 4 * q + j)] = (_Float16)hn[j];
        if (l == 3 && t == TSTEPS - 1) {
#pragma unroll
            for (int j = 0; j < 4; ++j)
                out[(size_t)(b0row + 4 * q + j) * 256 + u0] = hn[j];
        }
        __syncthreads();   // B2: An own-half ready (for publish read)

        // ---- ring backpressure before overwriting slot t ----
        if (l < 3 && t >= RING) wait_dn((unsigned)(t - RING + 1));

        // ---- publish own half of h(t) as tagged words ----
        {
            ull hv = *(const ull*)(An + po);
            ull* dst = hb_own + (size_t)(t & (RING - 1)) * SLOT_ULL + rr * 128 + wown;
            const ull tg = ((ull)(unsigned)(t + 1)) << 32;
            __hip_atomic_store(dst + 0, tg | (ull)(unsigned)hv,         __ATOMIC_RELAXED, SCOPE);
            __hip_atomic_store(dst + 1, tg | (ull)(unsigned)(hv >> 32), __ATOMIC_RELAXED, SCOPE);
        }

        // ---- stage 6: stage x(t+1); prefetch partner slot t ----
        if (t + 1 < TSTEPS) {
            if (tid < 256) stage_x(t + 1, An);
            const ull* sp = hb_own + (size_t)(t & (RING - 1)) * SLOT_ULL + rr * 128 + wpar;
            vh0 = __hip_atomic_load(sp + 0, __ATOMIC_RELAXED, SCOPE);
            vh1 = __hip_atomic_load(sp + 1, __ATOMIC_RELAXED, SCOPE);
        }
        __syncthreads();   // B3: step t fully consumed

        if (tid == 0)
            __hip_atomic_store(my_flag, (unsigned)(t + 1), __ATOMIC_RELAXED, SCOPE);
    }
}

extern "C" void kernel_launch(void* const* d_in, const int* in_sizes, int n_in,
                              void* d_out, int out_size, void* d_ws, size_t ws_size,
                              hipStream_t stream)
{
    const float* x     = (const float*)d_in[0];
    const float* k0    = (const float*)d_in[1];
    const float* rk0   = (const float*)d_in[2];
    const float* b0    = (const float*)d_in[3];
    const float* kern  = (const float*)d_in[4];
    const float* rkern = (const float*)d_in[5];
    const float* bias  = (const float*)d_in[6];
    float* out = (float*)d_out;

    char* ws = (char*)d_ws;
    _Float16*     Wp    = (_Float16*)(ws + WP_OFF);
    float*        Bp    = (float*)(ws + BP_OFF);
    unsigned int* flags = (unsigned int*)(ws + FLAG_OFF);
    ull*          hbuf  = (ull*)(ws + HBUF_OFF);

    hipMemsetAsync(flags, 0, FLAG_BYTES, stream);

    const int total = LAYERS * WPL + LAYERS * 1024;
    repack_kernel<<<(total + 255) / 256, 256, 0, stream>>>(k0, rk0, b0, kern, rkern, bias, Wp, Bp);

    gru_kernel<<<LAYERS * NCH * 2, 512, 0, stream>>>(x, Wp, Bp, hbuf, flags, out);
}